// Round 2
// 285.208 us; speedup vs baseline: 1.0540x; 1.0540x over previous
//
#include <hip/hip_runtime.h>

#define NN 50000
#define EE 200000
#define RR 4
#define SC_TOTAL (RR * NN)                 // 200000
#define NB_SCAN ((SC_TOTAL + 1023) / 1024) // 196
#define GTILE ((NN + 127) / 128)           // 391 row-tiles of 128 for gemm

typedef __attribute__((ext_vector_type(8))) short bf16x8;
typedef __attribute__((ext_vector_type(4))) float f32x4;

__device__ inline unsigned short f2bf(float x) {   // round-to-nearest-even
    unsigned int u = __float_as_uint(x);
    u += 0x7fffu + ((u >> 16) & 1u);
    return (unsigned short)(u >> 16);
}
__device__ inline float bflo(unsigned u) { return __uint_as_float(u << 16); }
__device__ inline float bfhi(unsigned u) { return __uint_as_float(u & 0xffff0000u); }

// ---------------------------------------------------------------------------
// init (block-range partitioned): featb [0,6250) | W1T [6250,6506) |
// W2T [6506,6634) | btab1 [6634,6642) | btab2 [6642,6646) |
// counts zero [6646,6842) | desc+ticket zero [6842,6843)
__global__ __launch_bounds__(256) void init_kernel(
    const float* __restrict__ feat, unsigned short* __restrict__ featb,
    const float* __restrict__ W1, const float* __restrict__ b1,
    const float* __restrict__ W2, const float* __restrict__ b2,
    unsigned short* __restrict__ W1T, unsigned short* __restrict__ W2T,
    float* __restrict__ btab1, float* __restrict__ btab2,
    int* __restrict__ counts, unsigned long long* __restrict__ desc,
    int* __restrict__ ticket)
{
    int b = blockIdx.x, t = threadIdx.x;
    if (b < 6250) {
        int i = (b * 256 + t) * 4;
        float4 v = *(const float4*)&feat[i];
        unsigned lo = (unsigned)f2bf(v.x) | ((unsigned)f2bf(v.y) << 16);
        unsigned hi = (unsigned)f2bf(v.z) | ((unsigned)f2bf(v.w) << 16);
        *(uint2*)&featb[i] = make_uint2(lo, hi);
    } else if (b < 6506) {
        int i = (b - 6250) * 256 + t;
        int j = i >> 9, kc = i & 511, r = kc >> 7, k = kc & 127;
        W1T[i] = f2bf(W1[r * 16384 + k * 128 + j]);
    } else if (b < 6634) {
        int i = (b - 6506) * 256 + t;
        int j = i >> 9, kc = i & 511, r = kc >> 7, k = kc & 127;
        W2T[i] = f2bf(W2[r * 8192 + k * 64 + j]);
    } else if (b < 6642) {
        int i = (b - 6634) * 256 + t;
        int mm = i >> 7, c = i & 127;
        float s = 0.f;
        #pragma unroll
        for (int r = 0; r < RR; ++r) if (mm & (1 << r)) s += b1[r * 128 + c];
        btab1[i] = s;
    } else if (b < 6646) {
        int i = (b - 6642) * 256 + t;
        int mm = i >> 6, c = i & 63;
        float s = 0.f;
        #pragma unroll
        for (int r = 0; r < RR; ++r) if (mm & (1 << r)) s += b2[r * 64 + c];
        btab2[i] = s;
    } else if (b < 6842) {
        int i = ((b - 6646) * 256 + t) * 4;
        if (i < SC_TOTAL) *(int4*)&counts[i] = make_int4(0, 0, 0, 0);
    } else {
        if (t < NB_SCAN) desc[t] = 0ULL;
        if (t == 0) *ticket = 0;
    }
}

// ---------------------------------------------------------------------------
// hist: 4 edges/thread (MLP=4)
__global__ __launch_bounds__(256) void hist_kernel(
    const int* __restrict__ edges, int* __restrict__ counts)
{
    int r = blockIdx.y;
    int e0 = blockIdx.x * 1024 + threadIdx.x;
    const int* ed = edges + (size_t)r * 2 * EE + EE;
    int d[4];
    #pragma unroll
    for (int k = 0; k < 4; ++k) {
        int e = e0 + k * 256;
        d[k] = (e < EE) ? ed[e] : -1;
    }
    #pragma unroll
    for (int k = 0; k < 4; ++k)
        if (d[k] >= 0) atomicAdd(&counts[r * NN + d[k]], 1);
}

// ---------------------------------------------------------------------------
// single-dispatch exclusive scan: decoupled lookback, ticket-ordered.
// Writes offsets[0..SC_TOTAL] (sentinel) and cursor copy.
__global__ __launch_bounds__(256) void scan_kernel(
    const int* __restrict__ counts, int* __restrict__ offsets,
    int* __restrict__ cur, unsigned long long* __restrict__ desc,
    int* __restrict__ ticket)
{
    __shared__ int lred[256];
    __shared__ int sbase, svb;
    const int t = threadIdx.x;
    if (t == 0) svb = atomicAdd(ticket, 1);
    __syncthreads();
    const int vb = svb;                 // virtual block id in dispatch order
    const int i0 = vb * 1024 + t * 4;

    int e0 = 0, e1 = 0, e2 = 0, e3 = 0;
    if (i0 + 3 < SC_TOTAL) { int4 v = *(const int4*)&counts[i0]; e0 = v.x; e1 = v.y; e2 = v.z; e3 = v.w; }
    else {
        if (i0     < SC_TOTAL) e0 = counts[i0];
        if (i0 + 1 < SC_TOTAL) e1 = counts[i0 + 1];
        if (i0 + 2 < SC_TOTAL) e2 = counts[i0 + 2];
        if (i0 + 3 < SC_TOTAL) e3 = counts[i0 + 3];
    }
    lred[t] = e0 + e1 + e2 + e3;
    __syncthreads();
    for (int o = 1; o < 256; o <<= 1) {
        int x = (t >= o) ? lred[t - o] : 0;
        __syncthreads();
        lred[t] += x;
        __syncthreads();
    }
    const int total = lred[255];

    if (t == 0) {
        if (vb == 0) {
            atomicExch(&desc[0], (2ULL << 32) | (unsigned)total);
            sbase = 0;
        } else {
            atomicExch(&desc[vb], (1ULL << 32) | (unsigned)total);
            int running = 0;
            int i = vb - 1;
            while (true) {
                unsigned long long d = atomicAdd(&desc[i], 0ULL);
                unsigned st = (unsigned)(d >> 32);
                if (st == 0) continue;                  // predecessor not ready
                running += (int)(d & 0xffffffffULL);
                if (st == 2) break;                     // found inclusive prefix
                --i;
            }
            atomicExch(&desc[vb], (2ULL << 32) | (unsigned)(running + total));
            sbase = running;
        }
        if (vb == 0) offsets[SC_TOTAL] = RR * EE;       // sentinel
    }
    __syncthreads();

    int base = sbase + ((t > 0) ? lred[t - 1] : 0);
    int o0 = base, o1 = base + e0, o2 = base + e0 + e1, o3 = base + e0 + e1 + e2;
    if (i0     < SC_TOTAL) { offsets[i0]     = o0; cur[i0]     = o0; }
    if (i0 + 1 < SC_TOTAL) { offsets[i0 + 1] = o1; cur[i0 + 1] = o1; }
    if (i0 + 2 < SC_TOTAL) { offsets[i0 + 2] = o2; cur[i0 + 2] = o2; }
    if (i0 + 3 < SC_TOTAL) { offsets[i0 + 3] = o3; cur[i0 + 3] = o3; }
}

// ---------------------------------------------------------------------------
// fill (blocks [0,784): dst-sorted ushort src, MLP=4) + mask (blocks [784,833))
__global__ __launch_bounds__(256) void fill_mask_kernel(
    const int* __restrict__ edges, int* __restrict__ cur,
    unsigned short* __restrict__ ssrc, const int* __restrict__ offsets,
    unsigned char* __restrict__ mask)
{
    int b = blockIdx.x, t = threadIdx.x;
    if (b < 784) {
        int r = b / 196, c = b - r * 196;
        int e0 = c * 1024 + t;
        const int* es = edges + (size_t)r * 2 * EE;
        int src[4], dst[4], p[4];
        #pragma unroll
        for (int k = 0; k < 4; ++k) {
            int e = e0 + k * 256;
            src[k] = (e < EE) ? es[e] : 0;
            dst[k] = (e < EE) ? es[EE + e] : -1;
        }
        #pragma unroll
        for (int k = 0; k < 4; ++k)
            if (dst[k] >= 0) p[k] = atomicAdd(&cur[r * NN + dst[k]], 1);
        #pragma unroll
        for (int k = 0; k < 4; ++k)
            if (dst[k] >= 0) ssrc[p[k]] = (unsigned short)src[k];
    } else {
        int v0 = ((b - 784) * 256 + t) * 4;
        #pragma unroll
        for (int k = 0; k < 4; ++k) {
            int v = v0 + k;
            if (v < NN) {
                unsigned m = 0;
                #pragma unroll
                for (int r = 0; r < RR; ++r)
                    if (offsets[r * NN + v + 1] > offsets[r * NN + v]) m |= (1u << r);
                mask[v] = (unsigned char)m;
            }
        }
    }
}

// ---------------------------------------------------------------------------
// segment gather-mean: quarter-wave (16 lanes x uint4 = 256B row) per
// (node,etype) segment; 4 independent segment streams per wave. Full N.
__global__ __launch_bounds__(256) void gather_seg(
    const unsigned short* __restrict__ X,   // [N,128] bf16
    const unsigned short* __restrict__ ssrc, const int* __restrict__ off,
    unsigned short* __restrict__ agg)       // [N,512] bf16
{
    int seg = blockIdx.x * 16 + (threadIdx.x >> 4);
    if (seg >= SC_TOTAL) return;
    int nl = seg >> 2;
    int r  = seg & 3;
    int l  = threadIdx.x & 15;
    int s = off[r * NN + nl];
    int e = off[r * NN + nl + 1];
    float a0 = 0.f, a1 = 0.f, a2 = 0.f, a3 = 0.f, a4 = 0.f, a5 = 0.f, a6 = 0.f, a7 = 0.f;
    int j = s;
    for (; j + 1 < e; j += 2) {
        int s0 = ssrc[j], s1 = ssrc[j + 1];
        uint4 u0 = *(const uint4*)&X[(size_t)s0 * 128 + l * 8];
        uint4 u1 = *(const uint4*)&X[(size_t)s1 * 128 + l * 8];
        a0 += bflo(u0.x) + bflo(u1.x); a1 += bfhi(u0.x) + bfhi(u1.x);
        a2 += bflo(u0.y) + bflo(u1.y); a3 += bfhi(u0.y) + bfhi(u1.y);
        a4 += bflo(u0.z) + bflo(u1.z); a5 += bfhi(u0.z) + bfhi(u1.z);
        a6 += bflo(u0.w) + bflo(u1.w); a7 += bfhi(u0.w) + bfhi(u1.w);
    }
    if (j < e) {
        uint4 u0 = *(const uint4*)&X[(size_t)ssrc[j] * 128 + l * 8];
        a0 += bflo(u0.x); a1 += bfhi(u0.x);
        a2 += bflo(u0.y); a3 += bfhi(u0.y);
        a4 += bflo(u0.z); a5 += bfhi(u0.z);
        a6 += bflo(u0.w); a7 += bfhi(u0.w);
    }
    float inv = (e > s) ? 1.0f / (float)(e - s) : 0.f;
    uint4 o;
    o.x = (unsigned)f2bf(a0 * inv) | ((unsigned)f2bf(a1 * inv) << 16);
    o.y = (unsigned)f2bf(a2 * inv) | ((unsigned)f2bf(a3 * inv) << 16);
    o.z = (unsigned)f2bf(a4 * inv) | ((unsigned)f2bf(a5 * inv) << 16);
    o.w = (unsigned)f2bf(a6 * inv) | ((unsigned)f2bf(a7 * inv) << 16);
    *(uint4*)&agg[(size_t)nl * 512 + r * 128 + l * 8] = o;
}

// ---------------------------------------------------------------------------
// W-resident GEMM: C[N x ON] = A[N x 512]_bf16 @ WT^T + btab[mask].
// Block = 128 rows x 64 cols. W panel (64 cols x 512 K bf16 = 64 KB) is staged
// ONCE into LDS (XOR-swizzled, no padding -> exactly 64 KB -> 2 blocks/CU),
// then the K-loop streams A fragments straight from global (each element read
// once, 16x64B fully-used lines) with ZERO barriers. Each wave owns 32 rows x
// 64 cols so every B ds_read_b128 feeds 2 MFMAs.
template<int ON, bool RELU_BF16>
__global__ __launch_bounds__(256) void gemm_wres(
    const unsigned short* __restrict__ A, const unsigned short* __restrict__ WT,
    const float* __restrict__ btab, const unsigned char* __restrict__ mask,
    void* __restrict__ Cout)
{
    __shared__ __align__(16) unsigned short Wl[64 * 512];   // 65536 B, swizzled
    const int tid  = threadIdx.x;
    const int wv   = tid >> 6;
    const int lane = tid & 63;
    const int m    = lane & 15;
    const int q    = lane >> 4;
    const int col0 = blockIdx.x * 64;       // 0 or 64 (layer1); 0 (layer2)
    const int row0 = blockIdx.y * 128;

    // ---- stage W panel once: linear global read, swizzled LDS write.
    // swizzle: byte-in-row ^= ((row&7)<<4)  (bijective within each row)
    #pragma unroll
    for (int i = 0; i < 16; ++i) {
        int L  = i * 4096 + tid * 16;       // linear byte in [64][1024]
        int nr = L >> 10, ir = L & 1023;
        uint4 v = *(const uint4*)((const char*)WT + ((size_t)(col0 + nr) << 10) + ir);
        *(uint4*)((char*)Wl + nr * 1024 + (ir ^ ((nr & 7) << 4))) = v;
    }
    __syncthreads();

    f32x4 acc[2][4];
    #pragma unroll
    for (int rf = 0; rf < 2; ++rf)
        #pragma unroll
        for (int nt = 0; nt < 4; ++nt) acc[rf][nt] = (f32x4){0.f, 0.f, 0.f, 0.f};

    const int ra0 = row0 + wv * 32 + m;       // rf=0 row
    const int ra1 = ra0 + 16;                 // rf=1 row
    const bool g0 = ra0 < NN, g1 = ra1 < NN;
    const unsigned short* Ap0 = A + (size_t)ra0 * 512 + q * 8;
    const unsigned short* Ap1 = A + (size_t)ra1 * 512 + q * 8;
    const bf16x8 bz = (bf16x8){0, 0, 0, 0, 0, 0, 0, 0};

    // ---- K loop: no barriers, no LDS writes. Compiler is free to hoist the
    // independent global A loads across iterations (latency hiding).
    #pragma unroll
    for (int kk = 0; kk < 16; ++kk) {
        bf16x8 a0 = g0 ? *(const bf16x8*)(Ap0 + kk * 32) : bz;
        bf16x8 a1 = g1 ? *(const bf16x8*)(Ap1 + kk * 32) : bz;
        bf16x8 bf[4];
        #pragma unroll
        for (int nt = 0; nt < 4; ++nt) {
            int off = (nt * 16 + m) * 1024 + ((kk * 64 + q * 16) ^ ((m & 7) << 4));
            bf[nt] = *(const bf16x8*)((const char*)Wl + off);
        }
        #pragma unroll
        for (int nt = 0; nt < 4; ++nt) {
            acc[0][nt] = __builtin_amdgcn_mfma_f32_16x16x32_bf16(a0, bf[nt], acc[0][nt], 0, 0, 0);
            acc[1][nt] = __builtin_amdgcn_mfma_f32_16x16x32_bf16(a1, bf[nt], acc[1][nt], 0, 0, 0);
        }
    }

    // ---- epilogue: bias-table + (relu->bf16 | fp32) store
    #pragma unroll
    for (int rf = 0; rf < 2; ++rf) {
        #pragma unroll
        for (int rg = 0; rg < 4; ++rg) {
            int row = row0 + wv * 32 + rf * 16 + q * 4 + rg;
            if (row < NN) {
                int mk = mask[row];
                #pragma unroll
                for (int nt = 0; nt < 4; ++nt) {
                    int col = col0 + nt * 16 + m;
                    float val = acc[rf][nt][rg] + btab[mk * ON + col];
                    if (RELU_BF16)
                        ((unsigned short*)Cout)[(size_t)row * ON + col] = f2bf(fmaxf(val, 0.f));
                    else
                        ((float*)Cout)[(size_t)row * ON + col] = val;
                }
            }
        }
    }
}

// ---------------------------------------------------------------------------
extern "C" void kernel_launch(void* const* d_in, const int* in_sizes, int n_in,
                              void* d_out, int out_size, void* d_ws, size_t ws_size,
                              hipStream_t stream)
{
    const float* feat  = (const float*)d_in[0];   // [N,128]
    const float* W1    = (const float*)d_in[1];   // [R,128,128]
    const float* b1    = (const float*)d_in[2];   // [R,128]
    const float* W2    = (const float*)d_in[3];   // [R,128,64]
    const float* b2    = (const float*)d_in[4];   // [R,64]
    const int*   edges = (const int*)d_in[5];     // [R,2,E]
    float* out = (float*)d_out;                   // [N,64] fp32

    // workspace (~82 MB of 256 MiB)
    char* p = (char*)d_ws;
    auto alloc = [&](size_t bytes) { char* q = p; p += (bytes + 255) & ~(size_t)255; return q; };
    int* counts              = (int*)alloc((size_t)SC_TOTAL * 4);
    int* offsets             = (int*)alloc((size_t)(SC_TOTAL + 4) * 4);
    int* cur                 = (int*)alloc((size_t)SC_TOTAL * 4);
    unsigned long long* desc = (unsigned long long*)alloc(NB_SCAN * 8);
    int* ticket              = (int*)alloc(256);
    unsigned short* ssrc     = (unsigned short*)alloc((size_t)RR * EE * 2);
    unsigned char* mask      = (unsigned char*)alloc(NN + 64);
    unsigned short* W1T      = (unsigned short*)alloc((size_t)128 * 512 * 2);
    unsigned short* W2T      = (unsigned short*)alloc((size_t)64 * 512 * 2);
    float* btab1             = (float*)alloc((size_t)16 * 128 * 4);
    float* btab2             = (float*)alloc((size_t)16 * 64 * 4);
    unsigned short* featb    = (unsigned short*)alloc((size_t)NN * 128 * 2);   // 12.8MB
    unsigned short* h1r      = (unsigned short*)alloc((size_t)NN * 128 * 2);   // 12.8MB
    unsigned short* agg      = (unsigned short*)alloc((size_t)NN * 512 * 2);   // 51.2MB

    // 1: featb + weight prep + zero (counts, desc, ticket)
    init_kernel<<<6843, 256, 0, stream>>>(feat, featb, W1, b1, W2, b2,
                                          W1T, W2T, btab1, btab2,
                                          counts, desc, ticket);
    // 2: degree histogram
    dim3 eg((EE + 1023) / 1024, RR);
    hist_kernel<<<eg, 256, 0, stream>>>(edges, counts);
    // 3: exclusive scan (decoupled lookback) -> offsets + cur
    scan_kernel<<<NB_SCAN, 256, 0, stream>>>(counts, offsets, cur, desc, ticket);
    // 4: dst-sorted src fill + deg>0 mask
    fill_mask_kernel<<<833, 256, 0, stream>>>(edges, cur, ssrc, offsets, mask);

    const int SEGB = SC_TOTAL / 16;   // 12500

    // 5-6: layer 1
    gather_seg<<<SEGB, 256, 0, stream>>>(featb, ssrc, offsets, agg);
    gemm_wres<128, true><<<dim3(2, GTILE), 256, 0, stream>>>(agg, W1T, btab1, mask, h1r);
    // 7-8: layer 2
    gather_seg<<<SEGB, 256, 0, stream>>>(h1r, ssrc, offsets, agg);
    gemm_wres<64, false><<<dim3(1, GTILE), 256, 0, stream>>>(agg, W2T, btab2, mask, out);
}

// Round 3
// 262.524 us; speedup vs baseline: 1.1451x; 1.0864x over previous
//
#include <hip/hip_runtime.h>

#define NN 50000
#define EE 200000
#define RR 4
#define SC_TOTAL (RR * NN)                 // 200000
#define NB_SCAN ((SC_TOTAL + 1023) / 1024) // 196
#define GTILE ((NN + 127) / 128)           // 391 row-tiles of 128 for gemm

typedef __attribute__((ext_vector_type(8))) short bf16x8;
typedef __attribute__((ext_vector_type(4))) float f32x4;

__device__ inline unsigned short f2bf(float x) {   // round-to-nearest-even
    unsigned int u = __float_as_uint(x);
    u += 0x7fffu + ((u >> 16) & 1u);
    return (unsigned short)(u >> 16);
}
__device__ inline float bflo(unsigned u) { return __uint_as_float(u << 16); }
__device__ inline float bfhi(unsigned u) { return __uint_as_float(u & 0xffff0000u); }

// ---------------------------------------------------------------------------
// init (block-range partitioned): featb [0,6250) | W1T [6250,6506) |
// W2T [6506,6634) | btab1 [6634,6642) | btab2 [6642,6646) |
// counts zero [6646,6842) | desc+ticket zero [6842,6843)
// W layouts are TRANSFORM-FIRST concat: WT[jout][k], jout = r*ON + j.
__global__ __launch_bounds__(256) void init_kernel(
    const float* __restrict__ feat, unsigned short* __restrict__ featb,
    const float* __restrict__ W1, const float* __restrict__ b1,
    const float* __restrict__ W2, const float* __restrict__ b2,
    unsigned short* __restrict__ W1T, unsigned short* __restrict__ W2T,
    float* __restrict__ btab1, float* __restrict__ btab2,
    int* __restrict__ counts, unsigned long long* __restrict__ desc,
    int* __restrict__ ticket)
{
    int b = blockIdx.x, t = threadIdx.x;
    if (b < 6250) {
        int i = (b * 256 + t) * 4;
        float4 v = *(const float4*)&feat[i];
        unsigned lo = (unsigned)f2bf(v.x) | ((unsigned)f2bf(v.y) << 16);
        unsigned hi = (unsigned)f2bf(v.z) | ((unsigned)f2bf(v.w) << 16);
        *(uint2*)&featb[i] = make_uint2(lo, hi);
    } else if (b < 6506) {
        // W1T[(r*128+j)*128 + k] = W1[r,k,j];  i in [0,65536)
        int i = (b - 6250) * 256 + t;
        int jout = i >> 7, k = i & 127;
        int r = jout >> 7, j = jout & 127;
        W1T[i] = f2bf(W1[r * 16384 + k * 128 + j]);
    } else if (b < 6634) {
        // W2T[(r*64+j)*128 + k] = W2[r,k,j];  i in [0,32768)
        int i = (b - 6506) * 256 + t;
        int jout = i >> 7, k = i & 127;
        int r = jout >> 6, j = jout & 63;
        W2T[i] = f2bf(W2[r * 8192 + k * 64 + j]);
    } else if (b < 6642) {
        int i = (b - 6634) * 256 + t;
        int mm = i >> 7, c = i & 127;
        float s = 0.f;
        #pragma unroll
        for (int r = 0; r < RR; ++r) if (mm & (1 << r)) s += b1[r * 128 + c];
        btab1[i] = s;
    } else if (b < 6646) {
        int i = (b - 6642) * 256 + t;
        int mm = i >> 6, c = i & 63;
        float s = 0.f;
        #pragma unroll
        for (int r = 0; r < RR; ++r) if (mm & (1 << r)) s += b2[r * 64 + c];
        btab2[i] = s;
    } else if (b < 6842) {
        int i = ((b - 6646) * 256 + t) * 4;
        if (i < SC_TOTAL) *(int4*)&counts[i] = make_int4(0, 0, 0, 0);
    } else {
        if (t < NB_SCAN) desc[t] = 0ULL;
        if (t == 0) *ticket = 0;
    }
}

// ---------------------------------------------------------------------------
// hist: 4 edges/thread (MLP=4)
__global__ __launch_bounds__(256) void hist_kernel(
    const int* __restrict__ edges, int* __restrict__ counts)
{
    int r = blockIdx.y;
    int e0 = blockIdx.x * 1024 + threadIdx.x;
    const int* ed = edges + (size_t)r * 2 * EE + EE;
    int d[4];
    #pragma unroll
    for (int k = 0; k < 4; ++k) {
        int e = e0 + k * 256;
        d[k] = (e < EE) ? ed[e] : -1;
    }
    #pragma unroll
    for (int k = 0; k < 4; ++k)
        if (d[k] >= 0) atomicAdd(&counts[r * NN + d[k]], 1);
}

// ---------------------------------------------------------------------------
// single-dispatch exclusive scan: decoupled lookback, ticket-ordered.
__global__ __launch_bounds__(256) void scan_kernel(
    const int* __restrict__ counts, int* __restrict__ offsets,
    int* __restrict__ cur, unsigned long long* __restrict__ desc,
    int* __restrict__ ticket)
{
    __shared__ int lred[256];
    __shared__ int sbase, svb;
    const int t = threadIdx.x;
    if (t == 0) svb = atomicAdd(ticket, 1);
    __syncthreads();
    const int vb = svb;                 // virtual block id in dispatch order
    const int i0 = vb * 1024 + t * 4;

    int e0 = 0, e1 = 0, e2 = 0, e3 = 0;
    if (i0 + 3 < SC_TOTAL) { int4 v = *(const int4*)&counts[i0]; e0 = v.x; e1 = v.y; e2 = v.z; e3 = v.w; }
    else {
        if (i0     < SC_TOTAL) e0 = counts[i0];
        if (i0 + 1 < SC_TOTAL) e1 = counts[i0 + 1];
        if (i0 + 2 < SC_TOTAL) e2 = counts[i0 + 2];
        if (i0 + 3 < SC_TOTAL) e3 = counts[i0 + 3];
    }
    lred[t] = e0 + e1 + e2 + e3;
    __syncthreads();
    for (int o = 1; o < 256; o <<= 1) {
        int x = (t >= o) ? lred[t - o] : 0;
        __syncthreads();
        lred[t] += x;
        __syncthreads();
    }
    const int total = lred[255];

    if (t == 0) {
        if (vb == 0) {
            atomicExch(&desc[0], (2ULL << 32) | (unsigned)total);
            sbase = 0;
        } else {
            atomicExch(&desc[vb], (1ULL << 32) | (unsigned)total);
            int running = 0;
            int i = vb - 1;
            while (true) {
                unsigned long long d = atomicAdd(&desc[i], 0ULL);
                unsigned st = (unsigned)(d >> 32);
                if (st == 0) continue;                  // predecessor not ready
                running += (int)(d & 0xffffffffULL);
                if (st == 2) break;                     // found inclusive prefix
                --i;
            }
            atomicExch(&desc[vb], (2ULL << 32) | (unsigned)(running + total));
            sbase = running;
        }
        if (vb == 0) offsets[SC_TOTAL] = RR * EE;       // sentinel
    }
    __syncthreads();

    int base = sbase + ((t > 0) ? lred[t - 1] : 0);
    int o0 = base, o1 = base + e0, o2 = base + e0 + e1, o3 = base + e0 + e1 + e2;
    if (i0     < SC_TOTAL) { offsets[i0]     = o0; cur[i0]     = o0; }
    if (i0 + 1 < SC_TOTAL) { offsets[i0 + 1] = o1; cur[i0 + 1] = o1; }
    if (i0 + 2 < SC_TOTAL) { offsets[i0 + 2] = o2; cur[i0 + 2] = o2; }
    if (i0 + 3 < SC_TOTAL) { offsets[i0 + 3] = o3; cur[i0 + 3] = o3; }
}

// ---------------------------------------------------------------------------
// fill (blocks [0,784): dst-sorted ushort src, MLP=4) + mask (blocks [784,833))
__global__ __launch_bounds__(256) void fill_mask_kernel(
    const int* __restrict__ edges, int* __restrict__ cur,
    unsigned short* __restrict__ ssrc, const int* __restrict__ offsets,
    unsigned char* __restrict__ mask)
{
    int b = blockIdx.x, t = threadIdx.x;
    if (b < 784) {
        int r = b / 196, c = b - r * 196;
        int e0 = c * 1024 + t;
        const int* es = edges + (size_t)r * 2 * EE;
        int src[4], dst[4], p[4];
        #pragma unroll
        for (int k = 0; k < 4; ++k) {
            int e = e0 + k * 256;
            src[k] = (e < EE) ? es[e] : 0;
            dst[k] = (e < EE) ? es[EE + e] : -1;
        }
        #pragma unroll
        for (int k = 0; k < 4; ++k)
            if (dst[k] >= 0) p[k] = atomicAdd(&cur[r * NN + dst[k]], 1);
        #pragma unroll
        for (int k = 0; k < 4; ++k)
            if (dst[k] >= 0) ssrc[p[k]] = (unsigned short)src[k];
    } else {
        int v0 = ((b - 784) * 256 + t) * 4;
        #pragma unroll
        for (int k = 0; k < 4; ++k) {
            int v = v0 + k;
            if (v < NN) {
                unsigned m = 0;
                #pragma unroll
                for (int r = 0; r < RR; ++r)
                    if (offsets[r * NN + v + 1] > offsets[r * NN + v]) m |= (1u << r);
                mask[v] = (unsigned char)m;
            }
        }
    }
}

// ---------------------------------------------------------------------------
// transform-first GEMM: H[N x OTOT] = A[N x 128]_bf16 @ WT^T (no bias).
// Block = 128 rows x 128 cols; W panel 128x128 bf16 = 32 KB LDS (XOR-swizzled),
// staged once, zero barriers in the K loop (K=128 -> 4 MFMA K-steps).
template<int OTOT>
__global__ __launch_bounds__(256) void gemm_tf(
    const unsigned short* __restrict__ A, const unsigned short* __restrict__ WT,
    unsigned short* __restrict__ H)
{
    __shared__ __align__(16) unsigned short Wl[128 * 128];   // 32768 B, swizzled
    const int tid  = threadIdx.x;
    const int wv   = tid >> 6;
    const int lane = tid & 63;
    const int m    = lane & 15;
    const int q    = lane >> 4;
    const int col0 = blockIdx.x * 128;
    const int row0 = blockIdx.y * 128;

    // stage W panel once: linear global read, swizzled LDS write
    #pragma unroll
    for (int i = 0; i < 8; ++i) {
        int L  = i * 4096 + tid * 16;       // linear byte in [128][256]
        int nr = L >> 8, ir = L & 255;
        uint4 v = *(const uint4*)((const char*)WT + ((size_t)(col0 + nr) << 8) + ir);
        *(uint4*)((char*)Wl + nr * 256 + (ir ^ ((nr & 7) << 4))) = v;
    }
    __syncthreads();

    f32x4 acc[2][8];
    #pragma unroll
    for (int rf = 0; rf < 2; ++rf)
        #pragma unroll
        for (int nt = 0; nt < 8; ++nt) acc[rf][nt] = (f32x4){0.f, 0.f, 0.f, 0.f};

    const int ra0 = row0 + wv * 32 + m;
    const int ra1 = ra0 + 16;
    const bool g0 = ra0 < NN, g1 = ra1 < NN;
    const unsigned short* Ap0 = A + (size_t)ra0 * 128 + q * 8;
    const unsigned short* Ap1 = A + (size_t)ra1 * 128 + q * 8;
    const bf16x8 bz = (bf16x8){0, 0, 0, 0, 0, 0, 0, 0};

    #pragma unroll
    for (int kk = 0; kk < 4; ++kk) {
        bf16x8 a0 = g0 ? *(const bf16x8*)(Ap0 + kk * 32) : bz;
        bf16x8 a1 = g1 ? *(const bf16x8*)(Ap1 + kk * 32) : bz;
        #pragma unroll
        for (int nt = 0; nt < 8; ++nt) {
            int offb = (nt * 16 + m) * 256 + ((kk * 64 + q * 16) ^ ((m & 7) << 4));
            bf16x8 bfr = *(const bf16x8*)((const char*)Wl + offb);
            acc[0][nt] = __builtin_amdgcn_mfma_f32_16x16x32_bf16(a0, bfr, acc[0][nt], 0, 0, 0);
            acc[1][nt] = __builtin_amdgcn_mfma_f32_16x16x32_bf16(a1, bfr, acc[1][nt], 0, 0, 0);
        }
    }

    #pragma unroll
    for (int rf = 0; rf < 2; ++rf) {
        #pragma unroll
        for (int rg = 0; rg < 4; ++rg) {
            int row = row0 + wv * 32 + rf * 16 + q * 4 + rg;
            if (row < NN) {
                unsigned short* Hp = H + (size_t)row * OTOT + col0 + m;
                #pragma unroll
                for (int nt = 0; nt < 8; ++nt)
                    Hp[nt * 16] = f2bf(acc[rf][nt][rg]);
            }
        }
    }
}

// ---------------------------------------------------------------------------
// gather-mean over TRANSFORMED rows, layer 1: 16 lanes per node; for each
// etype, mean of H1[src, r*128 .. r*128+128) (256B rows, uint4/lane); sum
// across etypes + btab1[mask] + relu -> h1r [N,128] bf16.
__global__ __launch_bounds__(256) void gather_node1(
    const unsigned short* __restrict__ H1, const unsigned short* __restrict__ ssrc,
    const int* __restrict__ off, const float* __restrict__ btab1,
    const unsigned char* __restrict__ mask, unsigned short* __restrict__ h1r)
{
    int n = blockIdx.x * 16 + (threadIdx.x >> 4);
    if (n >= NN) return;
    int l = threadIdx.x & 15;
    float a0 = 0.f, a1 = 0.f, a2 = 0.f, a3 = 0.f, a4 = 0.f, a5 = 0.f, a6 = 0.f, a7 = 0.f;
    #pragma unroll
    for (int r = 0; r < RR; ++r) {
        int s = off[r * NN + n];
        int e = off[r * NN + n + 1];
        if (e <= s) continue;
        const unsigned short* base = H1 + r * 128 + l * 8;
        float b0 = 0.f, b1v = 0.f, b2v = 0.f, b3 = 0.f, b4 = 0.f, b5 = 0.f, b6 = 0.f, b7 = 0.f;
        int j = s;
        for (; j + 1 < e; j += 2) {
            uint4 u0 = *(const uint4*)(base + (size_t)ssrc[j] * 512);
            uint4 u1 = *(const uint4*)(base + (size_t)ssrc[j + 1] * 512);
            b0 += bflo(u0.x) + bflo(u1.x); b1v += bfhi(u0.x) + bfhi(u1.x);
            b2v += bflo(u0.y) + bflo(u1.y); b3 += bfhi(u0.y) + bfhi(u1.y);
            b4 += bflo(u0.z) + bflo(u1.z); b5 += bfhi(u0.z) + bfhi(u1.z);
            b6 += bflo(u0.w) + bflo(u1.w); b7 += bfhi(u0.w) + bfhi(u1.w);
        }
        if (j < e) {
            uint4 u0 = *(const uint4*)(base + (size_t)ssrc[j] * 512);
            b0 += bflo(u0.x); b1v += bfhi(u0.x);
            b2v += bflo(u0.y); b3 += bfhi(u0.y);
            b4 += bflo(u0.z); b5 += bfhi(u0.z);
            b6 += bflo(u0.w); b7 += bfhi(u0.w);
        }
        float inv = 1.0f / (float)(e - s);
        a0 += b0 * inv; a1 += b1v * inv; a2 += b2v * inv; a3 += b3 * inv;
        a4 += b4 * inv; a5 += b5 * inv; a6 += b6 * inv; a7 += b7 * inv;
    }
    int mk = mask[n];
    const float* bt = btab1 + mk * 128 + l * 8;
    float4 t0 = *(const float4*)bt;
    float4 t1 = *(const float4*)(bt + 4);
    uint4 o;
    o.x = (unsigned)f2bf(fmaxf(a0 + t0.x, 0.f)) | ((unsigned)f2bf(fmaxf(a1 + t0.y, 0.f)) << 16);
    o.y = (unsigned)f2bf(fmaxf(a2 + t0.z, 0.f)) | ((unsigned)f2bf(fmaxf(a3 + t0.w, 0.f)) << 16);
    o.z = (unsigned)f2bf(fmaxf(a4 + t1.x, 0.f)) | ((unsigned)f2bf(fmaxf(a5 + t1.y, 0.f)) << 16);
    o.w = (unsigned)f2bf(fmaxf(a6 + t1.z, 0.f)) | ((unsigned)f2bf(fmaxf(a7 + t1.w, 0.f)) << 16);
    *(uint4*)&h1r[(size_t)n * 128 + l * 8] = o;
}

// ---------------------------------------------------------------------------
// gather-mean layer 2: 8 lanes per node; 128B transformed rows (r*64 cols);
// sum across etypes + btab2[mask] -> out [N,64] fp32 (final output).
__global__ __launch_bounds__(256) void gather_node2(
    const unsigned short* __restrict__ H2, const unsigned short* __restrict__ ssrc,
    const int* __restrict__ off, const float* __restrict__ btab2,
    const unsigned char* __restrict__ mask, float* __restrict__ out)
{
    int n = blockIdx.x * 32 + (threadIdx.x >> 3);
    if (n >= NN) return;
    int l = threadIdx.x & 7;
    float a0 = 0.f, a1 = 0.f, a2 = 0.f, a3 = 0.f, a4 = 0.f, a5 = 0.f, a6 = 0.f, a7 = 0.f;
    #pragma unroll
    for (int r = 0; r < RR; ++r) {
        int s = off[r * NN + n];
        int e = off[r * NN + n + 1];
        if (e <= s) continue;
        const unsigned short* base = H2 + r * 64 + l * 8;
        float b0 = 0.f, b1v = 0.f, b2v = 0.f, b3 = 0.f, b4 = 0.f, b5 = 0.f, b6 = 0.f, b7 = 0.f;
        int j = s;
        for (; j + 1 < e; j += 2) {
            uint4 u0 = *(const uint4*)(base + (size_t)ssrc[j] * 256);
            uint4 u1 = *(const uint4*)(base + (size_t)ssrc[j + 1] * 256);
            b0 += bflo(u0.x) + bflo(u1.x); b1v += bfhi(u0.x) + bfhi(u1.x);
            b2v += bflo(u0.y) + bflo(u1.y); b3 += bfhi(u0.y) + bfhi(u1.y);
            b4 += bflo(u0.z) + bflo(u1.z); b5 += bfhi(u0.z) + bfhi(u1.z);
            b6 += bflo(u0.w) + bflo(u1.w); b7 += bfhi(u0.w) + bfhi(u1.w);
        }
        if (j < e) {
            uint4 u0 = *(const uint4*)(base + (size_t)ssrc[j] * 256);
            b0 += bflo(u0.x); b1v += bfhi(u0.x);
            b2v += bflo(u0.y); b3 += bfhi(u0.y);
            b4 += bflo(u0.z); b5 += bfhi(u0.z);
            b6 += bflo(u0.w); b7 += bfhi(u0.w);
        }
        float inv = 1.0f / (float)(e - s);
        a0 += b0 * inv; a1 += b1v * inv; a2 += b2v * inv; a3 += b3 * inv;
        a4 += b4 * inv; a5 += b5 * inv; a6 += b6 * inv; a7 += b7 * inv;
    }
    int mk = mask[n];
    const float* bt = btab2 + mk * 64 + l * 8;
    float4 t0 = *(const float4*)bt;
    float4 t1 = *(const float4*)(bt + 4);
    float* op = out + (size_t)n * 64 + l * 8;
    *(float4*)op       = make_float4(a0 + t0.x, a1 + t0.y, a2 + t0.z, a3 + t0.w);
    *(float4*)(op + 4) = make_float4(a4 + t1.x, a5 + t1.y, a6 + t1.z, a7 + t1.w);
}

// ---------------------------------------------------------------------------
extern "C" void kernel_launch(void* const* d_in, const int* in_sizes, int n_in,
                              void* d_out, int out_size, void* d_ws, size_t ws_size,
                              hipStream_t stream)
{
    const float* feat  = (const float*)d_in[0];   // [N,128]
    const float* W1    = (const float*)d_in[1];   // [R,128,128]
    const float* b1    = (const float*)d_in[2];   // [R,128]
    const float* W2    = (const float*)d_in[3];   // [R,128,64]
    const float* b2    = (const float*)d_in[4];   // [R,64]
    const int*   edges = (const int*)d_in[5];     // [R,2,E]
    float* out = (float*)d_out;                   // [N,64] fp32

    char* p = (char*)d_ws;
    auto alloc = [&](size_t bytes) { char* q = p; p += (bytes + 255) & ~(size_t)255; return q; };
    int* counts              = (int*)alloc((size_t)SC_TOTAL * 4);
    int* offsets             = (int*)alloc((size_t)(SC_TOTAL + 4) * 4);
    int* cur                 = (int*)alloc((size_t)SC_TOTAL * 4);
    unsigned long long* desc = (unsigned long long*)alloc(NB_SCAN * 8);
    int* ticket              = (int*)alloc(256);
    unsigned short* ssrc     = (unsigned short*)alloc((size_t)RR * EE * 2);
    unsigned char* mask      = (unsigned char*)alloc(NN + 64);
    unsigned short* W1T      = (unsigned short*)alloc((size_t)512 * 128 * 2);
    unsigned short* W2T      = (unsigned short*)alloc((size_t)256 * 128 * 2);
    float* btab1             = (float*)alloc((size_t)16 * 128 * 4);
    float* btab2             = (float*)alloc((size_t)16 * 64 * 4);
    unsigned short* featb    = (unsigned short*)alloc((size_t)NN * 128 * 2);   // 12.8MB
    unsigned short* h1r      = (unsigned short*)alloc((size_t)NN * 128 * 2);   // 12.8MB
    unsigned short* H        = (unsigned short*)alloc((size_t)NN * 512 * 2);   // 51.2MB (H1; reused as H2)

    // 1: featb + weight prep + zero (counts, desc, ticket)
    init_kernel<<<6843, 256, 0, stream>>>(feat, featb, W1, b1, W2, b2,
                                          W1T, W2T, btab1, btab2,
                                          counts, desc, ticket);
    // 2: degree histogram
    dim3 eg((EE + 1023) / 1024, RR);
    hist_kernel<<<eg, 256, 0, stream>>>(edges, counts);
    // 3: exclusive scan (decoupled lookback) -> offsets + cur
    scan_kernel<<<NB_SCAN, 256, 0, stream>>>(counts, offsets, cur, desc, ticket);
    // 4: dst-sorted src fill + deg>0 mask
    fill_mask_kernel<<<833, 256, 0, stream>>>(edges, cur, ssrc, offsets, mask);

    // 5: H1 = featb @ W1cat  [N,512]
    gemm_tf<512><<<dim3(4, GTILE), 256, 0, stream>>>(featb, W1T, H);
    // 6: h1 = relu(sum_r mean_r(H1 slices) + btab1[mask])  [N,128] bf16
    gather_node1<<<(NN + 15) / 16, 256, 0, stream>>>(H, ssrc, offsets, btab1, mask, h1r);
    // 7: H2 = h1 @ W2cat  [N,256]
    gemm_tf<256><<<dim3(2, GTILE), 256, 0, stream>>>(h1r, W2T, H);
    // 8: out = sum_r mean_r(H2 slices) + btab2[mask]  [N,64] fp32
    gather_node2<<<(NN + 31) / 32, 256, 0, stream>>>(H, ssrc, offsets, btab2, mask, out);
}

// Round 4
// 228.548 us; speedup vs baseline: 1.3153x; 1.1487x over previous
//
#include <hip/hip_runtime.h>

#define NN 50000
#define EE 200000
#define RR 4
#define SC_TOTAL (RR * NN)                 // 200000 segments
#define CAP 32                             // max in-degree per (node,etype); P(exceed)~1e-19
#define GTILE ((NN + 127) / 128)           // 391 row-tiles of 128 for gemm

typedef __attribute__((ext_vector_type(8))) short bf16x8;
typedef __attribute__((ext_vector_type(4))) float f32x4;

__device__ inline unsigned short f2bf(float x) {   // round-to-nearest-even
    unsigned int u = __float_as_uint(x);
    u += 0x7fffu + ((u >> 16) & 1u);
    return (unsigned short)(u >> 16);
}
__device__ inline float bflo(unsigned u) { return __uint_as_float(u << 16); }
__device__ inline float bfhi(unsigned u) { return __uint_as_float(u & 0xffff0000u); }

// ---------------------------------------------------------------------------
// init (block-range partitioned): featb [0,6250) | W1T [6250,6506) |
// W2T [6506,6634) | btab1 [6634,6642) | btab2 [6642,6646) |
// cnt zero [6646,9771)  (cnt padded: one counter per 64B line, 3.2M ints)
// W layouts are TRANSFORM-FIRST concat: WT[jout][k], jout = r*ON + j.
__global__ __launch_bounds__(256) void init_kernel(
    const float* __restrict__ feat, unsigned short* __restrict__ featb,
    const float* __restrict__ W1, const float* __restrict__ b1,
    const float* __restrict__ W2, const float* __restrict__ b2,
    unsigned short* __restrict__ W1T, unsigned short* __restrict__ W2T,
    float* __restrict__ btab1, float* __restrict__ btab2,
    int* __restrict__ cnt)
{
    int b = blockIdx.x, t = threadIdx.x;
    if (b < 6250) {
        int i = (b * 256 + t) * 4;
        float4 v = *(const float4*)&feat[i];
        unsigned lo = (unsigned)f2bf(v.x) | ((unsigned)f2bf(v.y) << 16);
        unsigned hi = (unsigned)f2bf(v.z) | ((unsigned)f2bf(v.w) << 16);
        *(uint2*)&featb[i] = make_uint2(lo, hi);
    } else if (b < 6506) {
        // W1T[(r*128+j)*128 + k] = W1[r,k,j];  i in [0,65536)
        int i = (b - 6250) * 256 + t;
        int jout = i >> 7, k = i & 127;
        int r = jout >> 7, j = jout & 127;
        W1T[i] = f2bf(W1[r * 16384 + k * 128 + j]);
    } else if (b < 6634) {
        // W2T[(r*64+j)*128 + k] = W2[r,k,j];  i in [0,32768)
        int i = (b - 6506) * 256 + t;
        int jout = i >> 7, k = i & 127;
        int r = jout >> 6, j = jout & 63;
        W2T[i] = f2bf(W2[r * 8192 + k * 64 + j]);
    } else if (b < 6642) {
        int i = (b - 6634) * 256 + t;
        int mm = i >> 7, c = i & 127;
        float s = 0.f;
        #pragma unroll
        for (int r = 0; r < RR; ++r) if (mm & (1 << r)) s += b1[r * 128 + c];
        btab1[i] = s;
    } else if (b < 6646) {
        int i = (b - 6642) * 256 + t;
        int mm = i >> 6, c = i & 63;
        float s = 0.f;
        #pragma unroll
        for (int r = 0; r < RR; ++r) if (mm & (1 << r)) s += b2[r * 64 + c];
        btab2[i] = s;
    } else {
        // zero cnt: SC_TOTAL*16 ints = 3.2M, int4 per thread
        int i = ((b - 6646) * 256 + t) * 4;
        if (i < SC_TOTAL * 16) *(int4*)&cnt[i] = make_int4(0, 0, 0, 0);
    }
}

// ---------------------------------------------------------------------------
// fill_append: 1 edge/thread, 1 atomic + 1 store. Buckets: ssrc2[seg*CAP+p],
// counters padded to one per 64B line (cnt[seg*16]) to avoid same-line
// serialization at the coherence point.
__global__ __launch_bounds__(256) void fill_append(
    const int* __restrict__ edges, int* __restrict__ cnt,
    unsigned short* __restrict__ ssrc2)
{
    int r = blockIdx.y;
    int e = blockIdx.x * 256 + threadIdx.x;
    if (e >= EE) return;
    const int* es = edges + (size_t)r * 2 * EE;
    int src = es[e];
    int dst = es[EE + e];
    int seg = r * NN + dst;
    int p = atomicAdd(&cnt[seg * 16], 1);
    if (p < CAP) ssrc2[(size_t)seg * CAP + p] = (unsigned short)src;
}

// ---------------------------------------------------------------------------
// transform-first GEMM: H[N x OTOT] = A[N x 128]_bf16 @ WT^T (no bias).
// Block = 128 rows x 128 cols; W panel 128x128 bf16 = 32 KB LDS (XOR-swizzled),
// staged once, zero barriers in the K loop (K=128 -> 4 MFMA K-steps).
template<int OTOT>
__global__ __launch_bounds__(256) void gemm_tf(
    const unsigned short* __restrict__ A, const unsigned short* __restrict__ WT,
    unsigned short* __restrict__ H)
{
    __shared__ __align__(16) unsigned short Wl[128 * 128];   // 32768 B, swizzled
    const int tid  = threadIdx.x;
    const int wv   = tid >> 6;
    const int lane = tid & 63;
    const int m    = lane & 15;
    const int q    = lane >> 4;
    const int col0 = blockIdx.x * 128;
    const int row0 = blockIdx.y * 128;

    // stage W panel once: linear global read, swizzled LDS write
    #pragma unroll
    for (int i = 0; i < 8; ++i) {
        int L  = i * 4096 + tid * 16;       // linear byte in [128][256]
        int nr = L >> 8, ir = L & 255;
        uint4 v = *(const uint4*)((const char*)WT + ((size_t)(col0 + nr) << 8) + ir);
        *(uint4*)((char*)Wl + nr * 256 + (ir ^ ((nr & 7) << 4))) = v;
    }
    __syncthreads();

    f32x4 acc[2][8];
    #pragma unroll
    for (int rf = 0; rf < 2; ++rf)
        #pragma unroll
        for (int nt = 0; nt < 8; ++nt) acc[rf][nt] = (f32x4){0.f, 0.f, 0.f, 0.f};

    const int ra0 = row0 + wv * 32 + m;
    const int ra1 = ra0 + 16;
    const bool g0 = ra0 < NN, g1 = ra1 < NN;
    const unsigned short* Ap0 = A + (size_t)ra0 * 128 + q * 8;
    const unsigned short* Ap1 = A + (size_t)ra1 * 128 + q * 8;
    const bf16x8 bz = (bf16x8){0, 0, 0, 0, 0, 0, 0, 0};

    #pragma unroll
    for (int kk = 0; kk < 4; ++kk) {
        bf16x8 a0 = g0 ? *(const bf16x8*)(Ap0 + kk * 32) : bz;
        bf16x8 a1 = g1 ? *(const bf16x8*)(Ap1 + kk * 32) : bz;
        #pragma unroll
        for (int nt = 0; nt < 8; ++nt) {
            int offb = (nt * 16 + m) * 256 + ((kk * 64 + q * 16) ^ ((m & 7) << 4));
            bf16x8 bfr = *(const bf16x8*)((const char*)Wl + offb);
            acc[0][nt] = __builtin_amdgcn_mfma_f32_16x16x32_bf16(a0, bfr, acc[0][nt], 0, 0, 0);
            acc[1][nt] = __builtin_amdgcn_mfma_f32_16x16x32_bf16(a1, bfr, acc[1][nt], 0, 0, 0);
        }
    }

    #pragma unroll
    for (int rf = 0; rf < 2; ++rf) {
        #pragma unroll
        for (int rg = 0; rg < 4; ++rg) {
            int row = row0 + wv * 32 + rf * 16 + q * 4 + rg;
            if (row < NN) {
                unsigned short* Hp = H + (size_t)row * OTOT + col0 + m;
                #pragma unroll
                for (int nt = 0; nt < 8; ++nt)
                    Hp[nt * 16] = f2bf(acc[rf][nt][rg]);
            }
        }
    }
}

// ---------------------------------------------------------------------------
// gather-mean over TRANSFORMED rows, layer 1: 16 lanes per node; per etype,
// mean of H1[src, r*128 .. +128) (256B rows, uint4/lane); deg + bias-mask from
// cnt; sum across etypes + btab1[mk] + relu -> h1r [N,128] bf16.
__global__ __launch_bounds__(256) void gather_node1(
    const unsigned short* __restrict__ H1, const unsigned short* __restrict__ ssrc2,
    const int* __restrict__ cnt, const float* __restrict__ btab1,
    unsigned short* __restrict__ h1r)
{
    int n = blockIdx.x * 16 + (threadIdx.x >> 4);
    if (n >= NN) return;
    int l = threadIdx.x & 15;
    float a0 = 0.f, a1 = 0.f, a2 = 0.f, a3 = 0.f, a4 = 0.f, a5 = 0.f, a6 = 0.f, a7 = 0.f;
    int mk = 0;
    #pragma unroll
    for (int r = 0; r < RR; ++r) {
        int seg = r * NN + n;
        int deg = cnt[seg * 16];
        if (deg <= 0) continue;
        mk |= 1 << r;
        const unsigned short* lst  = ssrc2 + (size_t)seg * CAP;
        const unsigned short* base = H1 + r * 128 + l * 8;
        float b0 = 0.f, b1v = 0.f, b2v = 0.f, b3 = 0.f, b4 = 0.f, b5 = 0.f, b6 = 0.f, b7 = 0.f;
        int j = 0;
        for (; j + 1 < deg; j += 2) {
            uint4 u0 = *(const uint4*)(base + (size_t)lst[j] * 512);
            uint4 u1 = *(const uint4*)(base + (size_t)lst[j + 1] * 512);
            b0 += bflo(u0.x) + bflo(u1.x); b1v += bfhi(u0.x) + bfhi(u1.x);
            b2v += bflo(u0.y) + bflo(u1.y); b3 += bfhi(u0.y) + bfhi(u1.y);
            b4 += bflo(u0.z) + bflo(u1.z); b5 += bfhi(u0.z) + bfhi(u1.z);
            b6 += bflo(u0.w) + bflo(u1.w); b7 += bfhi(u0.w) + bfhi(u1.w);
        }
        if (j < deg) {
            uint4 u0 = *(const uint4*)(base + (size_t)lst[j] * 512);
            b0 += bflo(u0.x); b1v += bfhi(u0.x);
            b2v += bflo(u0.y); b3 += bfhi(u0.y);
            b4 += bflo(u0.z); b5 += bfhi(u0.z);
            b6 += bflo(u0.w); b7 += bfhi(u0.w);
        }
        float inv = 1.0f / (float)deg;
        a0 += b0 * inv; a1 += b1v * inv; a2 += b2v * inv; a3 += b3 * inv;
        a4 += b4 * inv; a5 += b5 * inv; a6 += b6 * inv; a7 += b7 * inv;
    }
    const float* bt = btab1 + mk * 128 + l * 8;
    float4 t0 = *(const float4*)bt;
    float4 t1 = *(const float4*)(bt + 4);
    uint4 o;
    o.x = (unsigned)f2bf(fmaxf(a0 + t0.x, 0.f)) | ((unsigned)f2bf(fmaxf(a1 + t0.y, 0.f)) << 16);
    o.y = (unsigned)f2bf(fmaxf(a2 + t0.z, 0.f)) | ((unsigned)f2bf(fmaxf(a3 + t0.w, 0.f)) << 16);
    o.z = (unsigned)f2bf(fmaxf(a4 + t1.x, 0.f)) | ((unsigned)f2bf(fmaxf(a5 + t1.y, 0.f)) << 16);
    o.w = (unsigned)f2bf(fmaxf(a6 + t1.z, 0.f)) | ((unsigned)f2bf(fmaxf(a7 + t1.w, 0.f)) << 16);
    *(uint4*)&h1r[(size_t)n * 128 + l * 8] = o;
}

// ---------------------------------------------------------------------------
// gather-mean layer 2: 8 lanes per node; 128B transformed rows (r*64 cols);
// sum across etypes + btab2[mk] -> out [N,64] fp32 (final output).
__global__ __launch_bounds__(256) void gather_node2(
    const unsigned short* __restrict__ H2, const unsigned short* __restrict__ ssrc2,
    const int* __restrict__ cnt, const float* __restrict__ btab2,
    float* __restrict__ out)
{
    int n = blockIdx.x * 32 + (threadIdx.x >> 3);
    if (n >= NN) return;
    int l = threadIdx.x & 7;
    float a0 = 0.f, a1 = 0.f, a2 = 0.f, a3 = 0.f, a4 = 0.f, a5 = 0.f, a6 = 0.f, a7 = 0.f;
    int mk = 0;
    #pragma unroll
    for (int r = 0; r < RR; ++r) {
        int seg = r * NN + n;
        int deg = cnt[seg * 16];
        if (deg <= 0) continue;
        mk |= 1 << r;
        const unsigned short* lst  = ssrc2 + (size_t)seg * CAP;
        const unsigned short* base = H2 + r * 64 + l * 8;
        float b0 = 0.f, b1v = 0.f, b2v = 0.f, b3 = 0.f, b4 = 0.f, b5 = 0.f, b6 = 0.f, b7 = 0.f;
        int j = 0;
        for (; j + 1 < deg; j += 2) {
            uint4 u0 = *(const uint4*)(base + (size_t)lst[j] * 256);
            uint4 u1 = *(const uint4*)(base + (size_t)lst[j + 1] * 256);
            b0 += bflo(u0.x) + bflo(u1.x); b1v += bfhi(u0.x) + bfhi(u1.x);
            b2v += bflo(u0.y) + bflo(u1.y); b3 += bfhi(u0.y) + bfhi(u1.y);
            b4 += bflo(u0.z) + bflo(u1.z); b5 += bfhi(u0.z) + bfhi(u1.z);
            b6 += bflo(u0.w) + bflo(u1.w); b7 += bfhi(u0.w) + bfhi(u1.w);
        }
        if (j < deg) {
            uint4 u0 = *(const uint4*)(base + (size_t)lst[j] * 256);
            b0 += bflo(u0.x); b1v += bfhi(u0.x);
            b2v += bflo(u0.y); b3 += bfhi(u0.y);
            b4 += bflo(u0.z); b5 += bfhi(u0.z);
            b6 += bflo(u0.w); b7 += bfhi(u0.w);
        }
        float inv = 1.0f / (float)deg;
        a0 += b0 * inv; a1 += b1v * inv; a2 += b2v * inv; a3 += b3 * inv;
        a4 += b4 * inv; a5 += b5 * inv; a6 += b6 * inv; a7 += b7 * inv;
    }
    const float* bt = btab2 + mk * 64 + l * 8;
    float4 t0 = *(const float4*)bt;
    float4 t1 = *(const float4*)(bt + 4);
    float* op = out + (size_t)n * 64 + l * 8;
    *(float4*)op       = make_float4(a0 + t0.x, a1 + t0.y, a2 + t0.z, a3 + t0.w);
    *(float4*)(op + 4) = make_float4(a4 + t1.x, a5 + t1.y, a6 + t1.z, a7 + t1.w);
}

// ---------------------------------------------------------------------------
extern "C" void kernel_launch(void* const* d_in, const int* in_sizes, int n_in,
                              void* d_out, int out_size, void* d_ws, size_t ws_size,
                              hipStream_t stream)
{
    const float* feat  = (const float*)d_in[0];   // [N,128]
    const float* W1    = (const float*)d_in[1];   // [R,128,128]
    const float* b1    = (const float*)d_in[2];   // [R,128]
    const float* W2    = (const float*)d_in[3];   // [R,128,64]
    const float* b2    = (const float*)d_in[4];   // [R,64]
    const int*   edges = (const int*)d_in[5];     // [R,2,E]
    float* out = (float*)d_out;                   // [N,64] fp32

    char* p = (char*)d_ws;
    auto alloc = [&](size_t bytes) { char* q = p; p += (bytes + 255) & ~(size_t)255; return q; };
    int* cnt                 = (int*)alloc((size_t)SC_TOTAL * 16 * 4);          // 12.8MB (padded)
    unsigned short* ssrc2    = (unsigned short*)alloc((size_t)SC_TOTAL * CAP * 2); // 12.8MB
    unsigned short* W1T      = (unsigned short*)alloc((size_t)512 * 128 * 2);
    unsigned short* W2T      = (unsigned short*)alloc((size_t)256 * 128 * 2);
    float* btab1             = (float*)alloc((size_t)16 * 128 * 4);
    float* btab2             = (float*)alloc((size_t)16 * 64 * 4);
    unsigned short* featb    = (unsigned short*)alloc((size_t)NN * 128 * 2);   // 12.8MB
    unsigned short* h1r      = (unsigned short*)alloc((size_t)NN * 128 * 2);   // 12.8MB
    unsigned short* H        = (unsigned short*)alloc((size_t)NN * 512 * 2);   // 51.2MB (H1; reused as H2)

    // 1: featb + weight prep + zero cnt
    init_kernel<<<9771, 256, 0, stream>>>(feat, featb, W1, b1, W2, b2,
                                          W1T, W2T, btab1, btab2, cnt);
    // 2: bucket-append edges (replaces hist+scan+fill+mask)
    dim3 fg((EE + 255) / 256, RR);
    fill_append<<<fg, 256, 0, stream>>>(edges, cnt, ssrc2);

    // 3: H1 = featb @ W1cat  [N,512]
    gemm_tf<512><<<dim3(4, GTILE), 256, 0, stream>>>(featb, W1T, H);
    // 4: h1 = relu(sum_r mean_r(H1 slices) + btab1[mk])  [N,128] bf16
    gather_node1<<<(NN + 15) / 16, 256, 0, stream>>>(H, ssrc2, cnt, btab1, h1r);
    // 5: H2 = h1 @ W2cat  [N,256]
    gemm_tf<256><<<dim3(2, GTILE), 256, 0, stream>>>(h1r, W2T, H);
    // 6: out = sum_r mean_r(H2 slices) + btab2[mk]  [N,64] fp32
    gather_node2<<<(NN + 31) / 32, 256, 0, stream>>>(H, ssrc2, cnt, btab2, out);
}

// Round 5
// 200.225 us; speedup vs baseline: 1.5014x; 1.1415x over previous
//
#include <hip/hip_runtime.h>

#define NN 50000
#define EE 200000
#define RR 4
#define SC_TOTAL (RR * NN)                 // 200000 segments
#define CAP 32                             // max in-degree per (node,etype); P(exceed)~1e-19
#define GTILE ((NN + 127) / 128)           // 391 row-tiles of 128 for gemm
#define NB_G1 (4 * GTILE)                  // 1564 gemm1 tiles (512 cols)
#define NB_F  1563                         // fill chunks (512 edges each, 2/thread)

typedef __attribute__((ext_vector_type(8))) short bf16x8;
typedef __attribute__((ext_vector_type(4))) float f32x4;

__device__ inline unsigned short f2bf(float x) {   // round-to-nearest-even
    unsigned int u = __float_as_uint(x);
    u += 0x7fffu + ((u >> 16) & 1u);
    return (unsigned short)(u >> 16);
}
__device__ inline float bflo(unsigned u) { return __uint_as_float(u << 16); }
__device__ inline float bfhi(unsigned u) { return __uint_as_float(u & 0xffff0000u); }

// ---------------------------------------------------------------------------
// init (block-range partitioned): featb [0,6250) | W1T [6250,6506) |
// W2T [6506,6634) | btab1 [6634,6642) | btab2 [6642,6646) |
// cnt zero [6646,6842)  (unpadded: 200K ints)
// W layouts are TRANSFORM-FIRST concat: WT[jout][k], jout = r*ON + j.
__global__ __launch_bounds__(256) void init_kernel(
    const float* __restrict__ feat, unsigned short* __restrict__ featb,
    const float* __restrict__ W1, const float* __restrict__ b1,
    const float* __restrict__ W2, const float* __restrict__ b2,
    unsigned short* __restrict__ W1T, unsigned short* __restrict__ W2T,
    float* __restrict__ btab1, float* __restrict__ btab2,
    int* __restrict__ cnt)
{
    int b = blockIdx.x, t = threadIdx.x;
    if (b < 6250) {
        int i = (b * 256 + t) * 4;
        float4 v = *(const float4*)&feat[i];
        unsigned lo = (unsigned)f2bf(v.x) | ((unsigned)f2bf(v.y) << 16);
        unsigned hi = (unsigned)f2bf(v.z) | ((unsigned)f2bf(v.w) << 16);
        *(uint2*)&featb[i] = make_uint2(lo, hi);
    } else if (b < 6506) {
        // W1T[(r*128+j)*128 + k] = W1[r,k,j];  i in [0,65536)
        int i = (b - 6250) * 256 + t;
        int jout = i >> 7, k = i & 127;
        int r = jout >> 7, j = jout & 127;
        W1T[i] = f2bf(W1[r * 16384 + k * 128 + j]);
    } else if (b < 6634) {
        // W2T[(r*64+j)*128 + k] = W2[r,k,j];  i in [0,32768)
        int i = (b - 6506) * 256 + t;
        int jout = i >> 7, k = i & 127;
        int r = jout >> 6, j = jout & 63;
        W2T[i] = f2bf(W2[r * 8192 + k * 64 + j]);
    } else if (b < 6642) {
        int i = (b - 6634) * 256 + t;
        int mm = i >> 7, c = i & 127;
        float s = 0.f;
        #pragma unroll
        for (int r = 0; r < RR; ++r) if (mm & (1 << r)) s += b1[r * 128 + c];
        btab1[i] = s;
    } else if (b < 6646) {
        int i = (b - 6642) * 256 + t;
        int mm = i >> 6, c = i & 63;
        float s = 0.f;
        #pragma unroll
        for (int r = 0; r < RR; ++r) if (mm & (1 << r)) s += b2[r * 64 + c];
        btab2[i] = s;
    } else {
        // zero cnt: 200K ints, int4 per thread
        int i = ((b - 6646) * 256 + t) * 4;
        if (i < SC_TOTAL) *(int4*)&cnt[i] = make_int4(0, 0, 0, 0);
    }
}

// ---------------------------------------------------------------------------
// FUSED fill + gemm1. Even blocks: one 128x128 tile of H1 = featb @ W1cat
// (MFMA/LDS-bound). Odd blocks: 512-edge bucket-append chunk (TCC-bound).
// 1:1 interleave -> resident mix from the start; the scatter's dead pipes
// are filled by the gemm waves. Only gather1 needs BOTH results.
__global__ __launch_bounds__(256) void fill_gemm1(
    const int* __restrict__ edges, int* __restrict__ cnt,
    unsigned short* __restrict__ ssrc2,
    const unsigned short* __restrict__ A, const unsigned short* __restrict__ WT,
    unsigned short* __restrict__ H)
{
    __shared__ __align__(16) unsigned short Wl[128 * 128];   // 32768 B (gemm path)
    const int bid = blockIdx.x;
    const int tid = threadIdx.x;

    if (bid & 1) {
        // ---- fill path: f in [0, NB_F), 2 edges/thread (independent chains)
        int f = bid >> 1;
        #pragma unroll
        for (int k = 0; k < 2; ++k) {
            int i = f * 512 + k * 256 + tid;
            if (i < RR * EE) {
                int r = i / EE;
                int e = i - r * EE;
                const int* es = edges + (size_t)r * 2 * EE;
                int src = es[e];
                int dst = es[EE + e];
                int seg = r * NN + dst;
                int p = atomicAdd(&cnt[seg], 1);
                if (p < CAP) ssrc2[(size_t)seg * CAP + p] = (unsigned short)src;
            }
        }
        return;
    }

    // ---- gemm path: g in [0, NB_G1); tile (col0, row0), OTOT=512
    const int g    = bid >> 1;
    const int wv   = tid >> 6;
    const int lane = tid & 63;
    const int m    = lane & 15;
    const int q    = lane >> 4;
    const int col0 = (g & 3) * 128;
    const int row0 = (g >> 2) * 128;

    // stage W panel once: linear global read, swizzled LDS write
    #pragma unroll
    for (int i = 0; i < 8; ++i) {
        int L  = i * 4096 + tid * 16;       // linear byte in [128][256]
        int nr = L >> 8, ir = L & 255;
        uint4 v = *(const uint4*)((const char*)WT + ((size_t)(col0 + nr) << 8) + ir);
        *(uint4*)((char*)Wl + nr * 256 + (ir ^ ((nr & 7) << 4))) = v;
    }
    __syncthreads();

    f32x4 acc[2][8];
    #pragma unroll
    for (int rf = 0; rf < 2; ++rf)
        #pragma unroll
        for (int nt = 0; nt < 8; ++nt) acc[rf][nt] = (f32x4){0.f, 0.f, 0.f, 0.f};

    const int ra0 = row0 + wv * 32 + m;
    const int ra1 = ra0 + 16;
    const bool g0 = ra0 < NN, g1 = ra1 < NN;
    const unsigned short* Ap0 = A + (size_t)ra0 * 128 + q * 8;
    const unsigned short* Ap1 = A + (size_t)ra1 * 128 + q * 8;
    const bf16x8 bz = (bf16x8){0, 0, 0, 0, 0, 0, 0, 0};

    #pragma unroll
    for (int kk = 0; kk < 4; ++kk) {
        bf16x8 a0 = g0 ? *(const bf16x8*)(Ap0 + kk * 32) : bz;
        bf16x8 a1 = g1 ? *(const bf16x8*)(Ap1 + kk * 32) : bz;
        #pragma unroll
        for (int nt = 0; nt < 8; ++nt) {
            int offb = (nt * 16 + m) * 256 + ((kk * 64 + q * 16) ^ ((m & 7) << 4));
            bf16x8 bfr = *(const bf16x8*)((const char*)Wl + offb);
            acc[0][nt] = __builtin_amdgcn_mfma_f32_16x16x32_bf16(a0, bfr, acc[0][nt], 0, 0, 0);
            acc[1][nt] = __builtin_amdgcn_mfma_f32_16x16x32_bf16(a1, bfr, acc[1][nt], 0, 0, 0);
        }
    }

    #pragma unroll
    for (int rf = 0; rf < 2; ++rf) {
        #pragma unroll
        for (int rg = 0; rg < 4; ++rg) {
            int row = row0 + wv * 32 + rf * 16 + q * 4 + rg;
            if (row < NN) {
                unsigned short* Hp = H + (size_t)row * 512 + col0 + m;
                #pragma unroll
                for (int nt = 0; nt < 8; ++nt)
                    Hp[nt * 16] = f2bf(acc[rf][nt][rg]);
            }
        }
    }
}

// ---------------------------------------------------------------------------
// transform-first GEMM (layer 2): H[N x OTOT] = A[N x 128]_bf16 @ WT^T.
template<int OTOT>
__global__ __launch_bounds__(256) void gemm_tf(
    const unsigned short* __restrict__ A, const unsigned short* __restrict__ WT,
    unsigned short* __restrict__ H)
{
    __shared__ __align__(16) unsigned short Wl[128 * 128];   // 32768 B, swizzled
    const int tid  = threadIdx.x;
    const int wv   = tid >> 6;
    const int lane = tid & 63;
    const int m    = lane & 15;
    const int q    = lane >> 4;
    const int col0 = blockIdx.x * 128;
    const int row0 = blockIdx.y * 128;

    #pragma unroll
    for (int i = 0; i < 8; ++i) {
        int L  = i * 4096 + tid * 16;       // linear byte in [128][256]
        int nr = L >> 8, ir = L & 255;
        uint4 v = *(const uint4*)((const char*)WT + ((size_t)(col0 + nr) << 8) + ir);
        *(uint4*)((char*)Wl + nr * 256 + (ir ^ ((nr & 7) << 4))) = v;
    }
    __syncthreads();

    f32x4 acc[2][8];
    #pragma unroll
    for (int rf = 0; rf < 2; ++rf)
        #pragma unroll
        for (int nt = 0; nt < 8; ++nt) acc[rf][nt] = (f32x4){0.f, 0.f, 0.f, 0.f};

    const int ra0 = row0 + wv * 32 + m;
    const int ra1 = ra0 + 16;
    const bool g0 = ra0 < NN, g1 = ra1 < NN;
    const unsigned short* Ap0 = A + (size_t)ra0 * 128 + q * 8;
    const unsigned short* Ap1 = A + (size_t)ra1 * 128 + q * 8;
    const bf16x8 bz = (bf16x8){0, 0, 0, 0, 0, 0, 0, 0};

    #pragma unroll
    for (int kk = 0; kk < 4; ++kk) {
        bf16x8 a0 = g0 ? *(const bf16x8*)(Ap0 + kk * 32) : bz;
        bf16x8 a1 = g1 ? *(const bf16x8*)(Ap1 + kk * 32) : bz;
        #pragma unroll
        for (int nt = 0; nt < 8; ++nt) {
            int offb = (nt * 16 + m) * 256 + ((kk * 64 + q * 16) ^ ((m & 7) << 4));
            bf16x8 bfr = *(const bf16x8*)((const char*)Wl + offb);
            acc[0][nt] = __builtin_amdgcn_mfma_f32_16x16x32_bf16(a0, bfr, acc[0][nt], 0, 0, 0);
            acc[1][nt] = __builtin_amdgcn_mfma_f32_16x16x32_bf16(a1, bfr, acc[1][nt], 0, 0, 0);
        }
    }

    #pragma unroll
    for (int rf = 0; rf < 2; ++rf) {
        #pragma unroll
        for (int rg = 0; rg < 4; ++rg) {
            int row = row0 + wv * 32 + rf * 16 + q * 4 + rg;
            if (row < NN) {
                unsigned short* Hp = H + (size_t)row * OTOT + col0 + m;
                #pragma unroll
                for (int nt = 0; nt < 8; ++nt)
                    Hp[nt * 16] = f2bf(acc[rf][nt][rg]);
            }
        }
    }
}

// ---------------------------------------------------------------------------
// gather-mean over TRANSFORMED rows, layer 1: 16 lanes per node; per etype,
// mean of H1[src, r*128 .. +128) (256B rows, uint4/lane); deg + bias-mask from
// cnt; sum across etypes + btab1[mk] + relu -> h1r [N,128] bf16.
__global__ __launch_bounds__(256) void gather_node1(
    const unsigned short* __restrict__ H1, const unsigned short* __restrict__ ssrc2,
    const int* __restrict__ cnt, const float* __restrict__ btab1,
    unsigned short* __restrict__ h1r)
{
    int n = blockIdx.x * 16 + (threadIdx.x >> 4);
    if (n >= NN) return;
    int l = threadIdx.x & 15;
    float a0 = 0.f, a1 = 0.f, a2 = 0.f, a3 = 0.f, a4 = 0.f, a5 = 0.f, a6 = 0.f, a7 = 0.f;
    int mk = 0;
    #pragma unroll
    for (int r = 0; r < RR; ++r) {
        int seg = r * NN + n;
        int deg = cnt[seg];
        if (deg <= 0) continue;
        mk |= 1 << r;
        int nd = (deg < CAP) ? deg : CAP;
        const unsigned short* lst  = ssrc2 + (size_t)seg * CAP;
        const unsigned short* base = H1 + r * 128 + l * 8;
        float b0 = 0.f, b1v = 0.f, b2v = 0.f, b3 = 0.f, b4 = 0.f, b5 = 0.f, b6 = 0.f, b7 = 0.f;
        int j = 0;
        for (; j + 1 < nd; j += 2) {
            uint4 u0 = *(const uint4*)(base + (size_t)lst[j] * 512);
            uint4 u1 = *(const uint4*)(base + (size_t)lst[j + 1] * 512);
            b0 += bflo(u0.x) + bflo(u1.x); b1v += bfhi(u0.x) + bfhi(u1.x);
            b2v += bflo(u0.y) + bflo(u1.y); b3 += bfhi(u0.y) + bfhi(u1.y);
            b4 += bflo(u0.z) + bflo(u1.z); b5 += bfhi(u0.z) + bfhi(u1.z);
            b6 += bflo(u0.w) + bflo(u1.w); b7 += bfhi(u0.w) + bfhi(u1.w);
        }
        if (j < nd) {
            uint4 u0 = *(const uint4*)(base + (size_t)lst[j] * 512);
            b0 += bflo(u0.x); b1v += bfhi(u0.x);
            b2v += bflo(u0.y); b3 += bfhi(u0.y);
            b4 += bflo(u0.z); b5 += bfhi(u0.z);
            b6 += bflo(u0.w); b7 += bfhi(u0.w);
        }
        float inv = 1.0f / (float)deg;
        a0 += b0 * inv; a1 += b1v * inv; a2 += b2v * inv; a3 += b3 * inv;
        a4 += b4 * inv; a5 += b5 * inv; a6 += b6 * inv; a7 += b7 * inv;
    }
    const float* bt = btab1 + mk * 128 + l * 8;
    float4 t0 = *(const float4*)bt;
    float4 t1 = *(const float4*)(bt + 4);
    uint4 o;
    o.x = (unsigned)f2bf(fmaxf(a0 + t0.x, 0.f)) | ((unsigned)f2bf(fmaxf(a1 + t0.y, 0.f)) << 16);
    o.y = (unsigned)f2bf(fmaxf(a2 + t0.z, 0.f)) | ((unsigned)f2bf(fmaxf(a3 + t0.w, 0.f)) << 16);
    o.z = (unsigned)f2bf(fmaxf(a4 + t1.x, 0.f)) | ((unsigned)f2bf(fmaxf(a5 + t1.y, 0.f)) << 16);
    o.w = (unsigned)f2bf(fmaxf(a6 + t1.z, 0.f)) | ((unsigned)f2bf(fmaxf(a7 + t1.w, 0.f)) << 16);
    *(uint4*)&h1r[(size_t)n * 128 + l * 8] = o;
}

// ---------------------------------------------------------------------------
// gather-mean layer 2: 8 lanes per node; 128B transformed rows (r*64 cols);
// sum across etypes + btab2[mk] -> out [N,64] fp32 (final output).
__global__ __launch_bounds__(256) void gather_node2(
    const unsigned short* __restrict__ H2, const unsigned short* __restrict__ ssrc2,
    const int* __restrict__ cnt, const float* __restrict__ btab2,
    float* __restrict__ out)
{
    int n = blockIdx.x * 32 + (threadIdx.x >> 3);
    if (n >= NN) return;
    int l = threadIdx.x & 7;
    float a0 = 0.f, a1 = 0.f, a2 = 0.f, a3 = 0.f, a4 = 0.f, a5 = 0.f, a6 = 0.f, a7 = 0.f;
    int mk = 0;
    #pragma unroll
    for (int r = 0; r < RR; ++r) {
        int seg = r * NN + n;
        int deg = cnt[seg];
        if (deg <= 0) continue;
        mk |= 1 << r;
        int nd = (deg < CAP) ? deg : CAP;
        const unsigned short* lst  = ssrc2 + (size_t)seg * CAP;
        const unsigned short* base = H2 + r * 64 + l * 8;
        float b0 = 0.f, b1v = 0.f, b2v = 0.f, b3 = 0.f, b4 = 0.f, b5 = 0.f, b6 = 0.f, b7 = 0.f;
        int j = 0;
        for (; j + 1 < nd; j += 2) {
            uint4 u0 = *(const uint4*)(base + (size_t)lst[j] * 256);
            uint4 u1 = *(const uint4*)(base + (size_t)lst[j + 1] * 256);
            b0 += bflo(u0.x) + bflo(u1.x); b1v += bfhi(u0.x) + bfhi(u1.x);
            b2v += bflo(u0.y) + bflo(u1.y); b3 += bfhi(u0.y) + bfhi(u1.y);
            b4 += bflo(u0.z) + bflo(u1.z); b5 += bfhi(u0.z) + bfhi(u1.z);
            b6 += bflo(u0.w) + bflo(u1.w); b7 += bfhi(u0.w) + bfhi(u1.w);
        }
        if (j < nd) {
            uint4 u0 = *(const uint4*)(base + (size_t)lst[j] * 256);
            b0 += bflo(u0.x); b1v += bfhi(u0.x);
            b2v += bflo(u0.y); b3 += bfhi(u0.y);
            b4 += bflo(u0.z); b5 += bfhi(u0.z);
            b6 += bflo(u0.w); b7 += bfhi(u0.w);
        }
        float inv = 1.0f / (float)deg;
        a0 += b0 * inv; a1 += b1v * inv; a2 += b2v * inv; a3 += b3 * inv;
        a4 += b4 * inv; a5 += b5 * inv; a6 += b6 * inv; a7 += b7 * inv;
    }
    const float* bt = btab2 + mk * 64 + l * 8;
    float4 t0 = *(const float4*)bt;
    float4 t1 = *(const float4*)(bt + 4);
    float* op = out + (size_t)n * 64 + l * 8;
    *(float4*)op       = make_float4(a0 + t0.x, a1 + t0.y, a2 + t0.z, a3 + t0.w);
    *(float4*)(op + 4) = make_float4(a4 + t1.x, a5 + t1.y, a6 + t1.z, a7 + t1.w);
}

// ---------------------------------------------------------------------------
extern "C" void kernel_launch(void* const* d_in, const int* in_sizes, int n_in,
                              void* d_out, int out_size, void* d_ws, size_t ws_size,
                              hipStream_t stream)
{
    const float* feat  = (const float*)d_in[0];   // [N,128]
    const float* W1    = (const float*)d_in[1];   // [R,128,128]
    const float* b1    = (const float*)d_in[2];   // [R,128]
    const float* W2    = (const float*)d_in[3];   // [R,128,64]
    const float* b2    = (const float*)d_in[4];   // [R,64]
    const int*   edges = (const int*)d_in[5];     // [R,2,E]
    float* out = (float*)d_out;                   // [N,64] fp32

    char* p = (char*)d_ws;
    auto alloc = [&](size_t bytes) { char* q = p; p += (bytes + 255) & ~(size_t)255; return q; };
    int* cnt                 = (int*)alloc((size_t)SC_TOTAL * 4);                  // 0.8MB
    unsigned short* ssrc2    = (unsigned short*)alloc((size_t)SC_TOTAL * CAP * 2); // 12.8MB
    unsigned short* W1T      = (unsigned short*)alloc((size_t)512 * 128 * 2);
    unsigned short* W2T      = (unsigned short*)alloc((size_t)256 * 128 * 2);
    float* btab1             = (float*)alloc((size_t)16 * 128 * 4);
    float* btab2             = (float*)alloc((size_t)16 * 64 * 4);
    unsigned short* featb    = (unsigned short*)alloc((size_t)NN * 128 * 2);   // 12.8MB
    unsigned short* h1r      = (unsigned short*)alloc((size_t)NN * 128 * 2);   // 12.8MB
    unsigned short* H        = (unsigned short*)alloc((size_t)NN * 512 * 2);   // 51.2MB (H1; reused as H2)

    // 1: featb + weight prep + zero cnt
    init_kernel<<<6842, 256, 0, stream>>>(feat, featb, W1, b1, W2, b2,
                                          W1T, W2T, btab1, btab2, cnt);
    // 2: FUSED bucket-append (odd blocks) + H1 = featb @ W1cat (even blocks)
    fill_gemm1<<<NB_G1 + NB_F, 256, 0, stream>>>(edges, cnt, ssrc2, featb, W1T, H);
    // 3: h1 = relu(sum_r mean_r(H1 slices) + btab1[mk])  [N,128] bf16
    gather_node1<<<(NN + 15) / 16, 256, 0, stream>>>(H, ssrc2, cnt, btab1, h1r);
    // 4: H2 = h1 @ W2cat  [N,256]
    gemm_tf<256><<<dim3(2, GTILE), 256, 0, stream>>>(h1r, W2T, H);
    // 5: out = sum_r mean_r(H2 slices) + btab2[mk]  [N,64] fp32
    gather_node2<<<(NN + 31) / 32, 256, 0, stream>>>(H, ssrc2, cnt, btab2, out);
}